// Round 5
// baseline (35.613 us; speedup 1.0000x reference)
//
#include <hip/hip_runtime.h>

// BFP quantization: [N=32, C=256, H=56, W=56] f32, blk=32 channels share an
// exponent at each (n,h,w). mantissa_bits=3 -> qmax=3, clip [-4,3],
// scale = 2^(floor(log2(maxabs)) - 2).
//
// Memory-bound. R2-R4 established: FETCH=50MB (L3 absorbs half the input),
// WRITE=100MB, dur pinned at 35.5us (4.3 TB/s) across three register
// strategies -> not register/reload limited. This round: float4 (16B/lane,
// 1KB/wave-instruction) to halve memory-instruction count and double the
// per-stream DRAM burst. 128-thread blocks keep the grid at 1568 blocks
// (same dispatch shape as the float2 version).

#define BLK   32
#define SPAT  3136        // 56*56
#define PAIRS 256         // N * C/BLK = 32 * 8
#define VEC   4
#define SPT   (SPAT / VEC)   // 784 float4-threads per pair
#define TPB   128

typedef float v4f __attribute__((ext_vector_type(4)));

__global__ __launch_bounds__(TPB) void bfp_act_kernel(
    const float* __restrict__ x, float* __restrict__ out)
{
    // 32-bit indexing: max offset = 256*32*3136 = 25.7M < 2^31
    const int gid  = blockIdx.x * TPB + (int)threadIdx.x;
    const int pair = gid / SPT;                 // magic-mul
    const int srem = gid - pair * SPT;
    const int base = pair * (BLK * SPAT) + srem * VEC;

    // Load 32 channels x 4 spatial positions (coalesced 16B/lane, 1KB/wave)
    v4f v[BLK];
    #pragma unroll
    for (int c = 0; c < BLK; ++c) {
        v[c] = *reinterpret_cast<const v4f*>(x + base + c * SPAT);
    }

    // Per-position block max of |x|
    v4f m = {0.0f, 0.0f, 0.0f, 0.0f};
    #pragma unroll
    for (int c = 0; c < BLK; ++c) {
        #pragma unroll
        for (int k = 0; k < 4; ++k) m[k] = fmaxf(m[k], fabsf(v[c][k]));
    }

    // floor(log2(m)) = frexp_exp(m) - 1 (exact, incl. denormals)
    // scale = 2^(e_floor - 2) = 2^(frexp_e - 3); inverse = 2^(3 - frexp_e)
    v4f s, inv;
    int zmask = 0;
    #pragma unroll
    for (int k = 0; k < 4; ++k) {
        int e;
        frexpf(m[k], &e);
        s[k]   = ldexpf(1.0f, e - 3);
        inv[k] = ldexpf(1.0f, 3 - e);
        if (!(m[k] > 0.0f)) zmask |= (1 << k);
    }

    #pragma unroll
    for (int c = 0; c < BLK; ++c) {
        v4f o;
        #pragma unroll
        for (int k = 0; k < 4; ++k) {
            float q = fminf(fmaxf(rintf(v[c][k] * inv[k]), -4.0f), 3.0f);
            o[k] = (zmask & (1 << k)) ? 0.0f : q * s[k];
        }
        __builtin_nontemporal_store(o, reinterpret_cast<v4f*>(out + base + c * SPAT));
    }
}

extern "C" void kernel_launch(void* const* d_in, const int* in_sizes, int n_in,
                              void* d_out, int out_size, void* d_ws, size_t ws_size,
                              hipStream_t stream)
{
    const float* x = (const float*)d_in[0];
    float* out = (float*)d_out;
    const int total_threads = PAIRS * SPT;             // 200704
    const int blocks = (total_threads + TPB - 1) / TPB; // 1568
    bfp_act_kernel<<<blocks, TPB, 0, stream>>>(x, out);
}